// Round 1
// baseline (1331.264 us; speedup 1.0000x reference)
//
#include <hip/hip_runtime.h>

#define NODES   64
#define FRAMES  4096
#define INCH    9
#define H1DIM   256
#define H2DIM   512
#define NEDGE   256

#define H1P     260   // pad: 260*4B = 1040B, 16B-aligned rows, breaks power-of-2 bank stride

// ---------------------------------------------------------------------------
// prep: build transposed normalized adjacency AT[m][n] = A[n][m], zero acc.
// Handles edge_index arriving as int32 OR int64 (detected via high words).
// ---------------------------------------------------------------------------
__global__ void prep_kernel(const int* __restrict__ ei,
                            float* __restrict__ AT,
                            float* __restrict__ acc)
{
    __shared__ float sA[NODES * NODES];
    __shared__ float dis[NODES];
    __shared__ int   deg[NODES];
    __shared__ int   flag;
    const int t = threadIdx.x;  // 256 threads
    if (t == 0) flag = 0;
    for (int i = t; i < NODES * NODES; i += 256) sA[i] = 0.f;
    if (t < NODES) deg[t] = 1;  // self-loop
    __syncthreads();
    // int64 little-endian => slots 1,3,...,511 are high words of src values (<64) => all 0.
    // int32 => those slots are 256 random values in [0,64): P(all zero) ~ 64^-256.
    if (ei[2 * t + 1] != 0) atomicOr(&flag, 1);
    __syncthreads();
    const bool is64 = (flag == 0);
    int s = 0, d = 0;
    if (t < NEDGE) {
        if (is64) { s = ei[2 * t];   d = ei[512 + 2 * t]; }
        else      { s = ei[t];       d = ei[NEDGE + t];   }
        atomicAdd(&deg[d], 1);
    }
    __syncthreads();
    if (t < NODES) dis[t] = rsqrtf((float)deg[t]);
    __syncthreads();
    if (t < NEDGE) atomicAdd(&sA[d * NODES + s], dis[s] * dis[d]);
    __syncthreads();
    if (t < NODES) sA[t * NODES + t] += dis[t] * dis[t];
    __syncthreads();
    for (int i = t; i < NODES * NODES; i += 256) {
        int m = i >> 6, n = i & 63;
        AT[i] = sA[n * NODES + m];   // AT[m][n] = A[n][m]
    }
    for (int i = t; i < H2DIM; i += 256) acc[i] = 0.f;
}

// ---------------------------------------------------------------------------
// One block per frame: fully fused GCN layer1 + layer2 + row-sum reduction.
// ---------------------------------------------------------------------------
__global__ __launch_bounds__(512)
void frame_kernel(const float* __restrict__ x,
                  const float* __restrict__ ATg,
                  const float* __restrict__ W1,
                  const float* __restrict__ b1,
                  const float* __restrict__ W2,
                  const float* __restrict__ b2,
                  float* __restrict__ acc)
{
    __shared__ __align__(16) float sAT[NODES][NODES];   // 16384 B
    __shared__ __align__(16) float sX [NODES][12];      //  3072 B
    __shared__ __align__(16) float sAX[NODES][12];      //  3072 B
    __shared__ __align__(16) float sH1 [NODES][H1P];    // 66560 B
    __shared__ __align__(16) float sAH1[NODES][H1P];    // 66560 B
    __shared__ float sPart[H2DIM];                      //  2048 B   => 157,696 B total

    const int t = threadIdx.x;
    const int f = blockIdx.x;

    // ---- load X_f (64x9) and AT (64x64) ----
    for (int i = t; i < NODES * INCH; i += 512) {
        int n = i / INCH, c = i % INCH;
        sX[n][c] = x[(n * FRAMES + f) * INCH + c];
    }
    for (int i = t; i < NODES * NODES; i += 512)
        sAT[i >> 6][i & 63] = ATg[i];
    if (t < H2DIM) sPart[t] = 0.f;
    __syncthreads();

    // ---- AX[n][c] = sum_m A[n][m] * X[m][c] ----
    for (int i = t; i < NODES * INCH; i += 512) {
        int n = i / INCH, c = i % INCH;
        float v = 0.f;
        for (int m = 0; m < NODES; ++m) v += sAT[m][n] * sX[m][c];
        sAX[n][c] = v;
    }
    __syncthreads();

    // ---- H1 = relu(AX @ W1 + b1): 64x256 ----
    {
        const int rg = t >> 5, cg = t & 31;
        const int n0 = rg * 4, j0 = cg * 8;
        float accl[4][8];
        #pragma unroll
        for (int r = 0; r < 4; ++r)
            #pragma unroll
            for (int cc = 0; cc < 8; ++cc) accl[r][cc] = 0.f;
        #pragma unroll
        for (int c = 0; c < INCH; ++c) {
            float4 w0 = *(const float4*)&W1[c * H1DIM + j0];
            float4 w1 = *(const float4*)&W1[c * H1DIM + j0 + 4];
            float wv[8] = {w0.x, w0.y, w0.z, w0.w, w1.x, w1.y, w1.z, w1.w};
            #pragma unroll
            for (int r = 0; r < 4; ++r) {
                float a = sAX[n0 + r][c];
                #pragma unroll
                for (int cc = 0; cc < 8; ++cc) accl[r][cc] += a * wv[cc];
            }
        }
        float4 bb0 = *(const float4*)&b1[j0];
        float4 bb1 = *(const float4*)&b1[j0 + 4];
        float bv[8] = {bb0.x, bb0.y, bb0.z, bb0.w, bb1.x, bb1.y, bb1.z, bb1.w};
        #pragma unroll
        for (int r = 0; r < 4; ++r) {
            float4 o0, o1;
            o0.x = fmaxf(accl[r][0] + bv[0], 0.f);
            o0.y = fmaxf(accl[r][1] + bv[1], 0.f);
            o0.z = fmaxf(accl[r][2] + bv[2], 0.f);
            o0.w = fmaxf(accl[r][3] + bv[3], 0.f);
            o1.x = fmaxf(accl[r][4] + bv[4], 0.f);
            o1.y = fmaxf(accl[r][5] + bv[5], 0.f);
            o1.z = fmaxf(accl[r][6] + bv[6], 0.f);
            o1.w = fmaxf(accl[r][7] + bv[7], 0.f);
            *(float4*)&sH1[n0 + r][j0]     = o0;
            *(float4*)&sH1[n0 + r][j0 + 4] = o1;
        }
    }
    __syncthreads();

    // ---- AH1[n][k] = sum_m A[n][m] * H1[m][k]; lane = row n, wave owns 32 k ----
    {
        const int w  = t >> 6;
        const int l  = t & 63;
        const int k0 = w * 32;
        float accl[32];
        #pragma unroll
        for (int k = 0; k < 32; ++k) accl[k] = 0.f;
        for (int m = 0; m < NODES; ++m) {
            float a = sAT[m][l];   // stride-1 across lanes, conflict-free
            #pragma unroll
            for (int q = 0; q < 8; ++q) {
                float4 h = *(const float4*)&sH1[m][k0 + q * 4];  // broadcast
                accl[q * 4 + 0] += a * h.x;
                accl[q * 4 + 1] += a * h.y;
                accl[q * 4 + 2] += a * h.z;
                accl[q * 4 + 3] += a * h.w;
            }
        }
        #pragma unroll
        for (int q = 0; q < 8; ++q) {
            float4 o;
            o.x = accl[q * 4 + 0]; o.y = accl[q * 4 + 1];
            o.z = accl[q * 4 + 2]; o.w = accl[q * 4 + 3];
            *(float4*)&sAH1[l][k0 + q * 4] = o;
        }
    }
    __syncthreads();

    // ---- H2 = relu(AH1 @ W2 + b2), reduced over rows into sPart ----
    {
        const int rg = t >> 5, cg = t & 31;
        const int n0 = rg * 4;
        #pragma unroll
        for (int jc = 0; jc < 2; ++jc) {
            const int j0 = jc * 256 + cg * 8;
            float accl[4][8];
            #pragma unroll
            for (int r = 0; r < 4; ++r)
                #pragma unroll
                for (int cc = 0; cc < 8; ++cc) accl[r][cc] = 0.f;

            for (int k0 = 0; k0 < H1DIM; k0 += 4) {
                float4 a0 = *(const float4*)&sAH1[n0 + 0][k0];
                float4 a1 = *(const float4*)&sAH1[n0 + 1][k0];
                float4 a2 = *(const float4*)&sAH1[n0 + 2][k0];
                float4 a3 = *(const float4*)&sAH1[n0 + 3][k0];
                float av[4][4] = {{a0.x, a0.y, a0.z, a0.w},
                                  {a1.x, a1.y, a1.z, a1.w},
                                  {a2.x, a2.y, a2.z, a2.w},
                                  {a3.x, a3.y, a3.z, a3.w}};
                #pragma unroll
                for (int kk = 0; kk < 4; ++kk) {
                    float4 w0 = *(const float4*)&W2[(k0 + kk) * H2DIM + j0];
                    float4 w1 = *(const float4*)&W2[(k0 + kk) * H2DIM + j0 + 4];
                    float wv[8] = {w0.x, w0.y, w0.z, w0.w, w1.x, w1.y, w1.z, w1.w};
                    #pragma unroll
                    for (int r = 0; r < 4; ++r)
                        #pragma unroll
                        for (int cc = 0; cc < 8; ++cc)
                            accl[r][cc] += av[r][kk] * wv[cc];
                }
            }
            float4 bb0 = *(const float4*)&b2[j0];
            float4 bb1 = *(const float4*)&b2[j0 + 4];
            float bv[8] = {bb0.x, bb0.y, bb0.z, bb0.w, bb1.x, bb1.y, bb1.z, bb1.w};
            #pragma unroll
            for (int cc = 0; cc < 8; ++cc) {
                float s = 0.f;
                #pragma unroll
                for (int r = 0; r < 4; ++r)
                    s += fmaxf(accl[r][cc] + bv[cc], 0.f);
                atomicAdd(&sPart[j0 + cc], s);
            }
        }
    }
    __syncthreads();
    if (t < H2DIM) atomicAdd(&acc[t], sPart[t]);
}

// ---------------------------------------------------------------------------
// head: out[c] = (acc/262144) . Wfc[:,c] + bfc[c]
// ---------------------------------------------------------------------------
__global__ void head_kernel(const float* __restrict__ acc,
                            const float* __restrict__ Wfc,
                            const float* __restrict__ bfc,
                            float* __restrict__ out)
{
    const int c = blockIdx.x * 256 + threadIdx.x;
    if (c >= H2DIM) return;
    const float scale = 1.0f / (64.0f * 4096.0f);
    float v = bfc[c];
    for (int j = 0; j < H2DIM; ++j)
        v = fmaf(acc[j] * scale, Wfc[j * H2DIM + c], v);
    out[c] = v;
}

extern "C" void kernel_launch(void* const* d_in, const int* in_sizes, int n_in,
                              void* d_out, int out_size, void* d_ws, size_t ws_size,
                              hipStream_t stream)
{
    const float* x   = (const float*)d_in[0];
    const int*   ei  = (const int*)  d_in[1];
    const float* W1  = (const float*)d_in[2];
    const float* b1  = (const float*)d_in[3];
    const float* W2  = (const float*)d_in[4];
    const float* b2  = (const float*)d_in[5];
    const float* Wfc = (const float*)d_in[6];
    const float* bfc = (const float*)d_in[7];
    float* out = (float*)d_out;

    float* AT  = (float*)d_ws;      // 4096 floats
    float* acc = AT + 4096;         // 512 floats

    prep_kernel <<<1,      256, 0, stream>>>(ei, AT, acc);
    frame_kernel<<<FRAMES, 512, 0, stream>>>(x, AT, W1, b1, W2, b2, acc);
    head_kernel <<<2,      256, 0, stream>>>(acc, Wfc, bfc, out);
}